// Round 2
// baseline (761.459 us; speedup 1.0000x reference)
//
#include <hip/hip_runtime.h>
#include <hip/hip_bf16.h>

// RWKV7 WKV chunked scan. T=4096, H=32, N=64. Output dtype: FLOAT32 (reference
// returns jnp.float32; harness doc says d_out follows reference output dtype).
//
// Pass 1: per (chunk c, head h): dual scan [P rows (wave 0); M rows (wave 1)],
//         thread = one row held in 64 VGPRs. Emits per-step y_local = P_t r_t
//         (fp32, into d_out y region) and rho = M_t r_t (ws), plus chunk-final
//         M_c, P_c (ws, stored transposed for coalesced stores).
// Pass 2: sequential chain over 64 chunks: S_c = S_{c-1} M_c + P_c; writes
//         S_before[c] (ws) and final state to d_out tail (fp32).
// Pass 3: y_t = y_local_t + S_before[c] @ rho_t (parallel fixup), fp32.
//
// ws tiers: fp32 scratch (needs 128 MiB) > bf16 scratch (64 MiB) > zero-scratch
// sequential fallback (correct but slow) — never writes out of bounds.

#define Tt 4096
#define Hh 32
#define Nn 64
#define Ll 64              // chunk length
#define Cc 64              // number of chunks
#define HN (Hh * Nn)       // 2048
#define NN (Nn * Nn)       // 4096

__device__ __forceinline__ float ldf(const float* p) { return *p; }
__device__ __forceinline__ float ldf(const __hip_bfloat16* p) { return __bfloat162float(*p); }
__device__ __forceinline__ void stf(float* p, float v) { *p = v; }
__device__ __forceinline__ void stf(__hip_bfloat16* p, float v) { *p = __float2bfloat16(v); }

// ---------------------------------------------------------------- pass 1
template <typename ST>
__global__ __launch_bounds__(128, 3)
void pass1_scan(const float* __restrict__ rr, const float* __restrict__ ww,
                const float* __restrict__ kk, const float* __restrict__ vv,
                const float* __restrict__ aa, const float* __restrict__ bb,
                float* __restrict__ ylocal,
                ST* __restrict__ rho, ST* __restrict__ Mt, ST* __restrict__ Pt)
{
    const int c    = blockIdx.x / Hh;
    const int h    = blockIdx.x % Hh;
    const int tid  = threadIdx.x;
    const int lane = tid & 63;
    const int wv   = tid >> 6;   // 0: P rows, 1: M rows

    __shared__ float lds[2][6][Nn];   // double-buffered per-step vectors w,k,a,b,r,v

    float S[Nn];
    #pragma unroll
    for (int j = 0; j < Nn; ++j) S[j] = 0.0f;
    if (wv) {
        #pragma unroll
        for (int j = 0; j < Nn; ++j) S[j] = (j == lane) ? 1.0f : 0.0f;  // M starts at I
    }

    // wave 0 stages {w,k,a} -> slots 0..2; wave 1 stages {b,r,v} -> slots 3..5
    const float* g0 = wv ? bb : ww;
    const float* g1 = wv ? rr : kk;
    const float* g2 = wv ? vv : aa;
    const int slot = wv * 3;

    int off = (c * Ll * Hh + h) * Nn + lane;
    float p0 = g0[off], p1 = g1[off], p2 = g2[off];

    for (int t = 0; t < Ll; ++t) {
        float* buf = &lds[t & 1][0][0];
        buf[(slot + 0) * Nn + lane] = p0;
        buf[(slot + 1) * Nn + lane] = p1;
        buf[(slot + 2) * Nn + lane] = p2;
        __syncthreads();
        if (t + 1 < Ll) {               // prefetch next step while computing this one
            const int off2 = off + HN;
            p0 = g0[off2]; p1 = g1[off2]; p2 = g2[off2];
        }
        const float* lw = buf;
        const float* lk = buf + 1 * Nn;
        const float* la = buf + 2 * Nn;
        const float* lb = buf + 3 * Nn;
        const float* lr = buf + 4 * Nn;
        const float* lv = buf + 5 * Nn;

        // sa = S_row . a   (pre-update state)
        float s0 = 0.f, s1 = 0.f, s2 = 0.f, s3 = 0.f;
        #pragma unroll
        for (int j = 0; j < Nn; j += 4) {
            s0 += S[j + 0] * la[j + 0];
            s1 += S[j + 1] * la[j + 1];
            s2 += S[j + 2] * la[j + 2];
            s3 += S[j + 3] * la[j + 3];
        }
        const float sa   = (s0 + s1) + (s2 + s3);
        const float vval = wv ? 0.0f : lv[lane];   // M-scan has no vk term

        // S = S*w + sa*b + v*k ; y = S_new . r
        float y0 = 0.f, y1 = 0.f, y2 = 0.f, y3 = 0.f;
        #pragma unroll
        for (int j = 0; j < Nn; j += 4) {
            S[j + 0] = S[j + 0] * lw[j + 0] + sa * lb[j + 0] + vval * lk[j + 0];
            S[j + 1] = S[j + 1] * lw[j + 1] + sa * lb[j + 1] + vval * lk[j + 1];
            S[j + 2] = S[j + 2] * lw[j + 2] + sa * lb[j + 2] + vval * lk[j + 2];
            S[j + 3] = S[j + 3] * lw[j + 3] + sa * lb[j + 3] + vval * lk[j + 3];
            y0 += S[j + 0] * lr[j + 0];
            y1 += S[j + 1] * lr[j + 1];
            y2 += S[j + 2] * lr[j + 2];
            y3 += S[j + 3] * lr[j + 3];
        }
        const float y = (y0 + y1) + (y2 + y3);
        if (wv == 0) ylocal[off] = y;        // y_local (fp32, in d_out y region)
        else         stf(&rho[off], y);      // rho = M_t r_t
        off += HN;
        // single barrier per step: next iter writes the other LDS buffer
    }

    // chunk-final P_c / M_c, stored transposed: [c][h][col j][row i]
    ST* outm = wv ? Mt : Pt;
    const size_t mb = ((size_t)(c * Hh) + h) * NN;
    #pragma unroll
    for (int j = 0; j < Nn; ++j) stf(&outm[mb + (size_t)j * Nn + lane], S[j]);
}

// ---------------------------------------------------------------- pass 2
template <typename ST>
__global__ __launch_bounds__(256, 1)
void pass2_chain(const ST* __restrict__ Mt, const ST* __restrict__ Pt,
                 const float* __restrict__ st0, ST* __restrict__ Sst,
                 float* __restrict__ sfin)
{
    const int h   = blockIdx.x >> 3;
    const int g   = blockIdx.x & 7;
    const int tid = threadIdx.x;
    const int li  = tid >> 5;          // 0..7 local row
    const int i   = g * 8 + li;        // global row
    const int j2  = (tid & 31) * 2;    // column pair

    __shared__ float Mlds[Nn][Nn + 4]; // [row k][col j]
    __shared__ float Slds[8][Nn + 1];  // [li][col]

    float s0 = st0[(h * Nn + i) * Nn + j2];
    float s1 = st0[(h * Nn + i) * Nn + j2 + 1];
    Slds[li][j2]     = s0;
    Slds[li][j2 + 1] = s1;

    // prefetch chunk 0: Mt flat index lin = col*64 + row; Pt[col*64 + row]
    float mpre[16];
    {
        const size_t mb = (size_t)h * NN;
        #pragma unroll
        for (int q = 0; q < 16; ++q) mpre[q] = ldf(&Mt[mb + (size_t)tid * 16 + q]);
    }
    float pp0 = ldf(&Pt[(size_t)h * NN + (size_t)j2 * Nn + i]);
    float pp1 = ldf(&Pt[(size_t)h * NN + (size_t)(j2 + 1) * Nn + i]);
    __syncthreads();

    for (int c = 0; c < Cc; ++c) {
        // S_before[c] out (row-major [i][j])
        const size_t sb = ((size_t)(c * Hh) + h) * NN;
        stf(&Sst[sb + (size_t)i * Nn + j2],     s0);
        stf(&Sst[sb + (size_t)i * Nn + j2 + 1], s1);

        // un-transpose prefetched Mt into Mlds[row][col]
        #pragma unroll
        for (int q = 0; q < 16; ++q) {
            const int lin = tid * 16 + q;          // lin = col*64 + row
            Mlds[lin & 63][lin >> 6] = mpre[q];
        }
        __syncthreads();

        float np0 = 0.f, np1 = 0.f;
        if (c + 1 < Cc) {                          // prefetch next chunk during k-loop
            const size_t mb2 = ((size_t)((c + 1) * Hh) + h) * NN;
            #pragma unroll
            for (int q = 0; q < 16; ++q) mpre[q] = ldf(&Mt[mb2 + (size_t)tid * 16 + q]);
            np0 = ldf(&Pt[mb2 + (size_t)j2 * Nn + i]);
            np1 = ldf(&Pt[mb2 + (size_t)(j2 + 1) * Nn + i]);
        }

        // newS[i][j] = sum_k S[i][k] * M[k][j] + P[i][j]
        float a0 = pp0, b0 = 0.f, a1 = pp1, b1 = 0.f;
        #pragma unroll
        for (int kq = 0; kq < Nn; kq += 2) {
            const float se = Slds[li][kq];
            const float so = Slds[li][kq + 1];
            a0 += se * Mlds[kq][j2];
            b0 += so * Mlds[kq + 1][j2];
            a1 += se * Mlds[kq][j2 + 1];
            b1 += so * Mlds[kq + 1][j2 + 1];
        }
        const float acc0 = a0 + b0, acc1 = a1 + b1;
        __syncthreads();
        Slds[li][j2]     = acc0;
        Slds[li][j2 + 1] = acc1;
        s0 = acc0; s1 = acc1;
        pp0 = np0; pp1 = np1;
        __syncthreads();
    }

    // final state -> d_out tail (fp32)
    sfin[(h * Nn + i) * Nn + j2]     = s0;
    sfin[(h * Nn + i) * Nn + j2 + 1] = s1;
}

// ---------------------------------------------------------------- pass 3
template <typename ST>
__global__ __launch_bounds__(256, 4)
void pass3_fix(const ST* __restrict__ rho, const ST* __restrict__ Sst,
               float* __restrict__ y)
{
    const int c    = blockIdx.x / Hh;
    const int h    = blockIdx.x % Hh;
    const int tid  = threadIdx.x;
    const int lane = tid & 63;   // output row i
    const int tq   = tid >> 6;   // 0..3

    __shared__ float Rlds[Ll][Nn];   // rho rows for this chunk

    {
        const int tl = tid >> 2;
        const int j0 = (tid & 3) * 16;
        const int gb = ((c * Ll + tl) * Hh + h) * Nn + j0;
        #pragma unroll
        for (int q = 0; q < 16; ++q) Rlds[tl][j0 + q] = ldf(&rho[gb + q]);
    }

    float Srow[Nn];  // S_before[c][h] row `lane`
    {
        const size_t sb = ((size_t)(c * Hh) + h) * NN + (size_t)lane * Nn;
        #pragma unroll
        for (int j = 0; j < Nn; ++j) Srow[j] = ldf(&Sst[sb + j]);
    }
    __syncthreads();

    for (int m = 0; m < 16; ++m) {
        const int tl = tq + m * 4;
        float a0 = 0.f, a1 = 0.f, a2 = 0.f, a3 = 0.f;
        #pragma unroll
        for (int j = 0; j < Nn; j += 4) {
            a0 += Srow[j + 0] * Rlds[tl][j + 0];
            a1 += Srow[j + 1] * Rlds[tl][j + 1];
            a2 += Srow[j + 2] * Rlds[tl][j + 2];
            a3 += Srow[j + 3] * Rlds[tl][j + 3];
        }
        const int oy = ((c * Ll + tl) * Hh + h) * Nn + lane;
        y[oy] = y[oy] + ((a0 + a1) + (a2 + a3));
    }
}

// ------------------------------------------- zero-scratch sequential fallback
__global__ __launch_bounds__(64, 1)
void seq_scan(const float* __restrict__ rr, const float* __restrict__ ww,
              const float* __restrict__ kk, const float* __restrict__ vv,
              const float* __restrict__ aa, const float* __restrict__ bb,
              const float* __restrict__ st0,
              float* __restrict__ y, float* __restrict__ sfin)
{
    const int h    = blockIdx.x;
    const int lane = threadIdx.x;          // row i

    __shared__ float lds[2][6][Nn];

    float S[Nn];
    #pragma unroll
    for (int j = 0; j < Nn; ++j) S[j] = st0[(h * Nn + lane) * Nn + j];

    int off = h * Nn + lane;
    float p0 = ww[off], p1 = kk[off], p2 = aa[off], p3 = bb[off], p4 = rr[off], p5 = vv[off];

    for (int t = 0; t < Tt; ++t) {
        float* buf = &lds[t & 1][0][0];
        buf[0 * Nn + lane] = p0;
        buf[1 * Nn + lane] = p1;
        buf[2 * Nn + lane] = p2;
        buf[3 * Nn + lane] = p3;
        buf[4 * Nn + lane] = p4;
        buf[5 * Nn + lane] = p5;
        __syncthreads();
        if (t + 1 < Tt) {
            const int o2 = off + HN;
            p0 = ww[o2]; p1 = kk[o2]; p2 = aa[o2]; p3 = bb[o2]; p4 = rr[o2]; p5 = vv[o2];
        }
        const float* lw = buf;
        const float* lk = buf + 1 * Nn;
        const float* la = buf + 2 * Nn;
        const float* lb = buf + 3 * Nn;
        const float* lr = buf + 4 * Nn;
        const float  vvl = buf[5 * Nn + lane];

        float sa = 0.f;
        #pragma unroll
        for (int j = 0; j < Nn; ++j) sa += S[j] * la[j];

        float yv = 0.f;
        #pragma unroll
        for (int j = 0; j < Nn; ++j) {
            S[j] = S[j] * lw[j] + sa * lb[j] + vvl * lk[j];
            yv += S[j] * lr[j];
        }
        y[off] = yv;
        off += HN;
    }

    #pragma unroll
    for (int j = 0; j < Nn; ++j) sfin[(h * Nn + lane) * Nn + j] = S[j];
}

// ---------------------------------------------------------------- launch
extern "C" void kernel_launch(void* const* d_in, const int* in_sizes, int n_in,
                              void* d_out, int out_size, void* d_ws, size_t ws_size,
                              hipStream_t stream)
{
    const float* r  = (const float*)d_in[0];
    const float* w  = (const float*)d_in[1];
    const float* k  = (const float*)d_in[2];
    const float* v  = (const float*)d_in[3];
    const float* a  = (const float*)d_in[4];
    const float* b  = (const float*)d_in[5];
    const float* st = (const float*)d_in[6];

    float* out  = (float*)d_out;
    float* yl   = out;                       // y region (also y_local scratch)
    float* sfin = out + (size_t)Tt * HN;     // S_final region

    const size_t nTHN = (size_t)Tt * HN;       // 8388608 (rho)
    const size_t nCH  = (size_t)Cc * Hh * NN;  // 8388608 (each of Mt, Pt, Sst)
    const size_t need = nTHN + 3 * nCH;        // scratch element count

    if (ws_size >= need * sizeof(float)) {
        float* ws  = (float*)d_ws;
        float* rho = ws;
        float* Mt  = ws + nTHN;
        float* Pt  = Mt + nCH;
        float* Ss  = Pt + nCH;
        hipLaunchKernelGGL((pass1_scan<float>), dim3(Cc * Hh), dim3(128), 0, stream,
                           r, w, k, v, a, b, yl, rho, Mt, Pt);
        hipLaunchKernelGGL((pass2_chain<float>), dim3(Hh * 8), dim3(256), 0, stream,
                           Mt, Pt, st, Ss, sfin);
        hipLaunchKernelGGL((pass3_fix<float>), dim3(Cc * Hh), dim3(256), 0, stream,
                           rho, Ss, out);
    } else if (ws_size >= need * sizeof(__hip_bfloat16)) {
        __hip_bfloat16* ws  = (__hip_bfloat16*)d_ws;
        __hip_bfloat16* rho = ws;
        __hip_bfloat16* Mt  = ws + nTHN;
        __hip_bfloat16* Pt  = Mt + nCH;
        __hip_bfloat16* Ss  = Pt + nCH;
        hipLaunchKernelGGL((pass1_scan<__hip_bfloat16>), dim3(Cc * Hh), dim3(128), 0, stream,
                           r, w, k, v, a, b, yl, rho, Mt, Pt);
        hipLaunchKernelGGL((pass2_chain<__hip_bfloat16>), dim3(Hh * 8), dim3(256), 0, stream,
                           Mt, Pt, st, Ss, sfin);
        hipLaunchKernelGGL((pass3_fix<__hip_bfloat16>), dim3(Cc * Hh), dim3(256), 0, stream,
                           rho, Ss, out);
    } else {
        // no usable scratch: correct-but-slow sequential scan
        hipLaunchKernelGGL(seq_scan, dim3(Hh), dim3(64), 0, stream,
                           r, w, k, v, a, b, st, yl, sfin);
    }
}